// Round 9
// baseline (623.438 us; speedup 1.0000x reference)
//
#include <hip/hip_runtime.h>

// LightGCN encoder on MI355X — round 16.
// Round 15 post-mortem: three structurally different pulls converge at
// 44.5-48.5 us -> random-row-gather service floor; 1-hop restriction of
// pull2 covers 82% of nodes (no win). Remaining lever: dispatch boundaries.
// r11's single-kernel failure is now understood: its spin did an ACQUIRE
// load PER POLL (L1/L2 invalidate per poll x 2048 blocks = coherence
// meltdown; FETCH unchanged, pure stall). Round 16 merges pull+pull+final
// into one persistent kernel with a fixed barrier:
//   - RELAXED polls (no cache-invalidate side effect) + s_sleep(64)
//   - ONE acquire load after the wait exits; release folded into fetch_add
//   - __launch_bounds__(256,8), 0 LDS, ~16-40 VGPR -> all 2048 blocks
//     co-resident (32 waves/CU, MORE latency hiding than the 5-dispatch
//     pull's 64% occupancy). bar reset by lgcn_bin each launch (replay-safe).
// bin / csr byte-identical to round 15. Guard: prop >= 300 us -> revert.
#define N_USERS 100000
#define N_NODES 150000
#define DIM 64
#define BATCH 4096
#define BSHIFT 8
#define BUCKET 256
#define NB 586                 // ceil(150000 / 256) buckets
#define NBP 768                // padded bucket count for the 3-per-thread scan
#define PAIRS_PER_BLK 2048     // undirected pairs per binning block
#define STRIP 4096             // directed edges (words) per strip
#define CAPSHIFT 13
#define CAP (1 << CAPSHIFT)    // packed slots per bucket (max ~6.3K used)
#define PROP_BLOCKS 2048
#define PROP_WAVES (PROP_BLOCKS * 4)   // 8192 waves == 2*BATCH

typedef unsigned short bf16_t;

static __device__ __forceinline__ float bf2f(bf16_t h) {
    return __uint_as_float(((unsigned)h) << 16);
}
static __device__ __forceinline__ bf16_t f2bf(float f) {  // round-nearest-even
    unsigned u = __float_as_uint(f);
    return (bf16_t)((u + 0x7FFFu + ((u >> 16) & 1u)) >> 16);
}

// --- Strip sort: LDS counting-sort of 4096 directed edges by bucket --------
// binned word = (local_dst[8b]<<18)|src. pos[k*(NB+1)+b] = run start of
// bucket b in strip k; pos[k*(NB+1)+NB] = edge count of strip k.
__global__ void __launch_bounds__(256)
lgcn_bin(const int* __restrict__ row, const int* __restrict__ col,
         int* __restrict__ pos, int* __restrict__ binned, int EH,
         int* __restrict__ bar) {
    __shared__ int cnt[NBP];
    __shared__ int sA[256], sB[256];
    __shared__ int base[NB + 2];
    __shared__ int stage[STRIP];
    int tid = threadIdx.x;
    int k = blockIdx.x;
    if (k == 0 && tid == 0) bar[0] = 0;        // reset prop grid barrier
    cnt[tid] = 0; cnt[tid + 256] = 0; cnt[tid + 512] = 0;
    __syncthreads();
    int e0 = k * PAIRS_PER_BLK;
    int e1 = min(EH, e0 + PAIRS_PER_BLK);
    int n = e1 - e0;                           // pairs (multiple of 4)
    int nq = n >> 2;
    const int4* r4 = (const int4*)(row + e0);
    const int4* c4 = (const int4*)(col + e0);
    for (int q = tid; q < nq; q += 256) {
        int4 r = r4[q]; int4 c = c4[q];
        atomicAdd(&cnt[r.x >> BSHIFT], 1); atomicAdd(&cnt[c.x >> BSHIFT], 1);
        atomicAdd(&cnt[r.y >> BSHIFT], 1); atomicAdd(&cnt[c.y >> BSHIFT], 1);
        atomicAdd(&cnt[r.z >> BSHIFT], 1); atomicAdd(&cnt[c.z >> BSHIFT], 1);
        atomicAdd(&cnt[r.w >> BSHIFT], 1); atomicAdd(&cnt[c.w >> BSHIFT], 1);
    }
    __syncthreads();
    // Exclusive scan over NBP buckets, 3 per thread.
    int c0 = cnt[3 * tid], c1 = cnt[3 * tid + 1], c2 = cnt[3 * tid + 2];
    int s = c0 + c1 + c2;
    sA[tid] = s;
    __syncthreads();
    int* c_ = sA; int* n_ = sB;
    for (int off = 1; off < 256; off <<= 1) {
        n_[tid] = (tid >= off) ? c_[tid] + c_[tid - off] : c_[tid];
        __syncthreads();
        int* t = c_; c_ = n_; n_ = t;
    }
    int excl = c_[tid] - s;
    if (3 * tid     <= NB) base[3 * tid]     = excl;
    if (3 * tid + 1 <= NB) base[3 * tid + 1] = excl + c0;
    if (3 * tid + 2 <= NB) base[3 * tid + 2] = excl + c0 + c1;
    __syncthreads();
    // pos table (coalesced) + LDS cursors (reuse cnt).
    for (int i = tid; i <= NB; i += 256) {
        pos[k * (NB + 1) + i] = base[i];
        cnt[i] = base[i];
    }
    __syncthreads();
    // LDS scatter (re-read pairs; L2-hot).
    for (int q = tid; q < nq; q += 256) {
        int4 r = r4[q]; int4 c = c4[q];
        int rr[4] = { r.x, r.y, r.z, r.w };
        int cc[4] = { c.x, c.y, c.z, c.w };
#pragma unroll
        for (int j = 0; j < 4; ++j) {
            int p1 = atomicAdd(&cnt[cc[j] >> BSHIFT], 1);
            stage[p1] = ((cc[j] & (BUCKET - 1)) << 18) | rr[j];
            int p2 = atomicAdd(&cnt[rr[j] >> BSHIFT], 1);
            stage[p2] = ((rr[j] & (BUCKET - 1)) << 18) | cc[j];
        }
    }
    __syncthreads();
    // Coalesced strip write-out.
    int m4 = (2 * n) >> 2;
    int4* dst = (int4*)(binned + k * STRIP);
    const int4* st4 = (const int4*)stage;
    for (int j = tid; j < m4; j += 256) dst[j] = st4[j];
}

// --- Per-bucket padded CSR + fused g0 init ---------------------------------
// Node segments padded to multiple of 4; pad slots = N_NODES (zero row).
// nodeinfo = {start, deg, bits(1/sqrt(da)), bits(sqrt(da))}.
// Scatter goes DIRECTLY to the block's private bucket region in 'packed'.
// Also writes g0 = norm*x (bf16) for this bucket's nodes + zero rows (blk 0).
__global__ void __launch_bounds__(256)
lgcn_build_csr(const int* __restrict__ pos, const int* __restrict__ binned,
               int4* __restrict__ nodeinfo, int* __restrict__ packed,
               const float* __restrict__ ue, const float* __restrict__ ie,
               bf16_t* __restrict__ g0, bf16_t* __restrict__ g1, int nblk) {
    __shared__ int stage[CAP];     // gathered edges of this bucket (32 KB)
    __shared__ int sA[256], sB[256];
    __shared__ int hist[256], cur[256];
    int b = blockIdx.x;
    int tid = threadIdx.x;
    int gb = b << CAPSHIFT;        // this block's private packed region
    // Runs for strips tid and tid+256.
    int a0 = 0, l0 = 0, a1 = 0, l1 = 0;
    if (tid < nblk) {
        const int* pk = pos + tid * (NB + 1) + b;
        a0 = pk[0]; l0 = pk[1] - a0;
    }
    if (tid + 256 < nblk) {
        const int* pk = pos + (tid + 256) * (NB + 1) + b;
        a1 = pk[0]; l1 = pk[1] - a1;
    }
    int u = l0 + l1;
    sA[tid] = u;
    __syncthreads();
    int* c_ = sA; int* n_ = sB;
    for (int off = 1; off < 256; off <<= 1) {
        n_[tid] = (tid >= off) ? c_[tid] + c_[tid - off] : c_[tid];
        __syncthreads();
        int* t = c_; c_ = n_; n_ = t;
    }
    int myBase = c_[tid] - u;
    int Eb = c_[255];
    __syncthreads();
    // Gather runs into stage (short scattered reads, x4 unrolled for MLP).
    {
        const int* s0 = binned + tid * STRIP + a0;
        int i = 0;
        for (; i + 4 <= l0; i += 4) {
            int w0 = s0[i], w1 = s0[i + 1], w2 = s0[i + 2], w3 = s0[i + 3];
            stage[myBase + i] = w0;     stage[myBase + i + 1] = w1;
            stage[myBase + i + 2] = w2; stage[myBase + i + 3] = w3;
        }
        for (; i < l0; ++i) stage[myBase + i] = s0[i];
        const int* s1 = binned + (tid + 256) * STRIP + a1;
        int bb = myBase + l0;
        i = 0;
        for (; i + 4 <= l1; i += 4) {
            int w0 = s1[i], w1 = s1[i + 1], w2 = s1[i + 2], w3 = s1[i + 3];
            stage[bb + i] = w0;     stage[bb + i + 1] = w1;
            stage[bb + i + 2] = w2; stage[bb + i + 3] = w3;
        }
        for (; i < l1; ++i) stage[bb + i] = s1[i];
    }
    hist[tid] = 0;
    __syncthreads();
    for (int j = tid; j < Eb; j += 256)
        atomicAdd(&hist[stage[j] >> 18], 1);
    __syncthreads();
    int deg = hist[tid];
    int degp = (deg + 3) & ~3;               // padded segment length
    sA[tid] = degp;
    __syncthreads();
    int* c2 = sA; int* n2 = sB;
    for (int off = 1; off < 256; off <<= 1) {
        n2[tid] = (tid >= off) ? c2[tid] + c2[tid - off] : c2[tid];
        __syncthreads();
        int* t = c2; c2 = n2; n2 = t;
    }
    int startLoc = c2[tid] - degp;           // local, int4-aligned
    cur[tid] = startLoc;
    int node = (b << BSHIFT) + tid;
    float da = (deg == 0) ? 1.0f : (float)deg;
    float sq = sqrtf(da);
    float nm = 1.0f / sq;
    if (node < N_NODES) {
        int4 ni;
        ni.x = gb + startLoc;
        ni.y = deg;
        ni.z = __float_as_int(nm);
        ni.w = __float_as_int(sq);
        nodeinfo[node] = ni;
    }
    __syncthreads();                          // all hist reads done
    hist[tid] = __float_as_int(nm);           // reuse hist as norm table
    // Pad slots -> zero row (block-owned region; disjoint from scatter).
    for (int kk = deg; kk < degp; ++kk)
        packed[gb + startLoc + kk] = N_NODES;
    // Direct global scatter into the block's private bucket region.
    for (int j = tid; j < Eb; j += 256) {
        int w = stage[j];
        int p = atomicAdd(&cur[w >> 18], 1);  // LDS atomic
        packed[gb + p] = w & 0x3FFFF;
    }
    // --- Fused g0 init for this bucket's nodes (flat chunk range is
    // contiguous: t = b*4096 + i, i in [0, nloc*16)). -----------------------
    int firstNode = b << BSHIFT;
    int nloc = min(BUCKET, N_NODES - firstNode);
    const int nU16 = N_USERS * (DIM / 4);
    int t0 = firstNode * (DIM / 4);
    for (int i = tid; i < nloc * (DIM / 4); i += 256) {
        int t = t0 + i;
        float4 x = (t < nU16) ? ((const float4*)ue)[t]
                              : ((const float4*)ie)[t - nU16];
        float nrm = __int_as_float(hist[i >> 4]);
        ushort4 o;
        o.x = f2bf(x.x * nrm); o.y = f2bf(x.y * nrm);
        o.z = f2bf(x.z * nrm); o.w = f2bf(x.w * nrm);
        ((ushort4*)g0)[t] = o;
    }
    if (b == 0 && tid < 32) {                 // zero rows in both buffers
        const int nT = N_NODES * (DIM / 4);
        if (tid < 16) ((ushort4*)g0)[nT + tid] = make_ushort4(0, 0, 0, 0);
        else          ((ushort4*)g1)[nT + tid - 16] = make_ushort4(0, 0, 0, 0);
    }
}

// --- Propagation (persistent, lane = dim) ----------------------------------

// Sum rows of g for edges [su, su+dp): wave-uniform su/dp (SGPR), scalar
// edge-quad loads, saddr row reads with loop-invariant lane offset.
static __device__ __forceinline__ float
gather_lane(const bf16_t* __restrict__ g, const int* __restrict__ packed,
            int su, int dp, int lane) {
    float acc = 0.f;
    const int4* p4 = (const int4*)(packed + su);
    int k = 0;
    for (; k + 8 <= dp; k += 8) {            // 8 independent row loads
        int4 ea = p4[k >> 2];
        int4 eb = p4[(k >> 2) + 1];
        const bf16_t* r0 = g + ((unsigned)ea.x << 6);
        const bf16_t* r1 = g + ((unsigned)ea.y << 6);
        const bf16_t* r2 = g + ((unsigned)ea.z << 6);
        const bf16_t* r3 = g + ((unsigned)ea.w << 6);
        const bf16_t* r4 = g + ((unsigned)eb.x << 6);
        const bf16_t* r5 = g + ((unsigned)eb.y << 6);
        const bf16_t* r6 = g + ((unsigned)eb.z << 6);
        const bf16_t* r7 = g + ((unsigned)eb.w << 6);
        float v0 = bf2f(r0[lane]); float v1 = bf2f(r1[lane]);
        float v2 = bf2f(r2[lane]); float v3 = bf2f(r3[lane]);
        float v4 = bf2f(r4[lane]); float v5 = bf2f(r5[lane]);
        float v6 = bf2f(r6[lane]); float v7 = bf2f(r7[lane]);
        acc += ((v0 + v1) + (v2 + v3)) + ((v4 + v5) + (v6 + v7));
    }
    if (k < dp) {                            // tail quad (dp % 8 == 4)
        int4 ea = p4[k >> 2];
        const bf16_t* r0 = g + ((unsigned)ea.x << 6);
        const bf16_t* r1 = g + ((unsigned)ea.y << 6);
        const bf16_t* r2 = g + ((unsigned)ea.z << 6);
        const bf16_t* r3 = g + ((unsigned)ea.w << 6);
        float v0 = bf2f(r0[lane]); float v1 = bf2f(r1[lane]);
        float v2 = bf2f(r2[lane]); float v3 = bf2f(r3[lane]);
        acc += (v0 + v1) + (v2 + v3);
    }
    return acc;
}

// Grid barrier, r11-meltdown-proof: RELAXED polls (no cache-invalidate side
// effect) + s_sleep(64); exactly ONE acquire load after the wait exits;
// release folded into the arrival fetch_add.
static __device__ __forceinline__ void
grid_barrier(int* bar, int target) {
    __syncthreads();
    if (threadIdx.x == 0) {
        __hip_atomic_fetch_add(bar, 1, __ATOMIC_RELEASE,
                               __HIP_MEMORY_SCOPE_AGENT);
        while (__hip_atomic_load(bar, __ATOMIC_RELAXED,
                                 __HIP_MEMORY_SCOPE_AGENT) < target)
            __builtin_amdgcn_s_sleep(64);
        (void)__hip_atomic_load(bar, __ATOMIC_ACQUIRE,
                                __HIP_MEMORY_SCOPE_AGENT);
    }
    __syncthreads();
}

// pull1 (gB = P(gA)) | barrier | pull2 (gA = P(gB)) | barrier | final.
// 2048 blocks x 256 thr, 0 LDS, <=64 VGPR -> all co-resident (no deadlock).
__global__ void __launch_bounds__(256, 8)
lgcn_prop(bf16_t* __restrict__ gA, bf16_t* __restrict__ gB,
          const int4* __restrict__ nodeinfo, const int* __restrict__ packed,
          const float* __restrict__ ue, const float* __restrict__ ie,
          const int* __restrict__ uid, const int* __restrict__ iid,
          float* __restrict__ out, int* bar) {
    int gw = blockIdx.x * 4 + (threadIdx.x >> 6);
    int lane = threadIdx.x & 63;
    // pull 1: g1 = P(g0)
    for (int n0 = gw; n0 < N_NODES; n0 += PROP_WAVES) {
        int n = __builtin_amdgcn_readfirstlane(n0);
        int4 ni = nodeinfo[n];
        int su = __builtin_amdgcn_readfirstlane(ni.x);
        int du = __builtin_amdgcn_readfirstlane(ni.y);
        int dp = (du + 3) & ~3;
        float acc = gather_lane(gA, packed, su, dp, lane);
        float nm = __int_as_float(ni.z);
        gB[((unsigned)n << 6) + lane] = f2bf(acc * nm * nm);
    }
    grid_barrier(bar, PROP_BLOCKS);
    // pull 2: g2 = P(g1)
    for (int n0 = gw; n0 < N_NODES; n0 += PROP_WAVES) {
        int n = __builtin_amdgcn_readfirstlane(n0);
        int4 ni = nodeinfo[n];
        int su = __builtin_amdgcn_readfirstlane(ni.x);
        int du = __builtin_amdgcn_readfirstlane(ni.y);
        int dp = (du + 3) & ~3;
        float acc = gather_lane(gB, packed, su, dp, lane);
        float nm = __int_as_float(ni.z);
        gA[((unsigned)n << 6) + lane] = f2bf(acc * nm * nm);
    }
    grid_barrier(bar, 2 * PROP_BLOCKS);
    // final: one slot per wave (8192 waves == 2*BATCH)
    int slot = gw;
    if (slot < 2 * BATCH) {
        slot = __builtin_amdgcn_readfirstlane(slot);
        int isItem = slot >= BATCH;
        int b = isItem ? (slot - BATCH) : slot;
        int node = isItem ? (N_USERS + iid[b]) : uid[b];
        node = __builtin_amdgcn_readfirstlane(node);
        int4 ni = nodeinfo[node];
        int su = __builtin_amdgcn_readfirstlane(ni.x);
        int du = __builtin_amdgcn_readfirstlane(ni.y);
        int dp = (du + 3) & ~3;
        float acc = gather_lane(gA, packed, su, dp, lane);
        const float* xb = isItem ? (ie + ((unsigned)(node - N_USERS) << 6))
                                 : (ue + ((unsigned)node << 6));
        float x = xb[lane];
        float a1 = bf2f(gB[((unsigned)node << 6) + lane]);
        float a2 = bf2f(gA[((unsigned)node << 6) + lane]);
        float rn = __int_as_float(ni.w);
        float nm = __int_as_float(ni.z);
        out[((unsigned)slot << 6) + lane] =
            0.25f * (x + rn * (a1 + a2) + nm * acc);
    }
}

// --- Launch ----------------------------------------------------------------

extern "C" void kernel_launch(void* const* d_in, const int* in_sizes, int n_in,
                              void* d_out, int out_size, void* d_ws, size_t ws_size,
                              hipStream_t stream) {
    const float* ue  = (const float*)d_in[0];
    const float* ie  = (const float*)d_in[1];
    const int*   ei  = (const int*)d_in[3];
    const int*   uid = (const int*)d_in[4];
    const int*   iid = (const int*)d_in[5];
    float* out = (float*)d_out;

    const int E  = in_sizes[2];     // 2,000,000 directed edges
    const int EH = E / 2;           // 1,000,000 undirected pairs
    const int* row = ei;            // first-half src = user ids
    const int* col = ei + E;        // first-half dst = item node ids

    const int nblk = (EH + PAIRS_PER_BLK - 1) / PAIRS_PER_BLK;   // 489

    // Workspace carve-up (256-B aligned), ~58 MB total.
    char* p = (char*)d_ws;
    size_t off = 0;
    auto carve = [&](size_t bytes) -> char* {
        char* r = p + off;
        off += (bytes + 255) & ~(size_t)255;
        return r;
    };
    const size_t nodeBf16 = (size_t)(N_NODES + 1) * DIM * sizeof(bf16_t); // +zero row
    bf16_t* gA       = (bf16_t*)carve(nodeBf16);
    bf16_t* gB       = (bf16_t*)carve(nodeBf16);
    int4*   nodeinfo = (int4*)carve((size_t)N_NODES * sizeof(int4));       // 2.4 MB
    int*    pos      = (int*)carve((size_t)nblk * (NB + 1) * sizeof(int)); // 1.15 MB
    int*    binned   = (int*)carve((size_t)nblk * STRIP * sizeof(int));    // 8 MB
    int*    packed   = (int*)carve((size_t)NB * CAP * sizeof(int));        // 19.2 MB
    int*    bar      = (int*)carve(256);
    (void)ws_size;

    // 1) Strip sort (also resets the prop grid barrier).
    lgcn_bin<<<nblk, 256, 0, stream>>>(row, col, pos, binned, EH, bar);
    // 2) Per-bucket CSR (direct scatter) + fused g0 init + zero rows.
    lgcn_build_csr<<<NB, 256, 0, stream>>>(pos, binned, nodeinfo, packed,
                                           ue, ie, gA, gB, nblk);
    // 3) Persistent propagation: pull1 | barrier | pull2 | barrier | final.
    lgcn_prop<<<PROP_BLOCKS, 256, 0, stream>>>(gA, gB, nodeinfo, packed,
                                               ue, ie, uid, iid, out, bar);
}

// Round 10
// 232.131 us; speedup vs baseline: 2.6857x; 2.6857x over previous
//
#include <hip/hip_runtime.h>

// LightGCN encoder on MI355X — round 17.
// Round 16 post-mortem: persistent-kernel grid barriers are structurally
// impossible on gfx950 — agent-scope release/acquire forces per-XCD L2
// writeback/invalidate (L2s non-coherent); 2048 blocks x 2 barriers ~ 400 us
// regardless of poll discipline (relaxed polls changed nothing). Closed.
// Reverted to the proven 5-dispatch r15 structure.
// This round's single change: BIPARTITE PHASE SPLIT of each pull.
//   Item-dst edges gather only user rows (12.8 MB); user-dst edges gather
//   only item rows (6.4 MB). Two temporally-separated ranged dispatches per
//   layer shrink the live source set per pass -> higher L2 residence hit.
//   Same kernel body, same per-node order (absmax bit-identical), +2
//   dispatches (cheap per r12's measurement).
// Prediction: per-layer pull 44.5us/90MB-fill -> ~(19+14)us / ~55-65MB.
// Falsification: phases sum ~45us & fill ~90MB -> pull is request-rate
// floored; only the blocked-SpMM rewrite remains.
#define N_USERS 100000
#define N_NODES 150000
#define DIM 64
#define BATCH 4096
#define BSHIFT 8
#define BUCKET 256
#define NB 586                 // ceil(150000 / 256) buckets
#define NBP 768                // padded bucket count for the 3-per-thread scan
#define PAIRS_PER_BLK 2048     // undirected pairs per binning block
#define STRIP 4096             // directed edges (words) per strip
#define CAPSHIFT 13
#define CAP (1 << CAPSHIFT)    // packed slots per bucket (max ~6.3K used)

typedef unsigned short bf16_t;

static __device__ __forceinline__ float bf2f(bf16_t h) {
    return __uint_as_float(((unsigned)h) << 16);
}
static __device__ __forceinline__ bf16_t f2bf(float f) {  // round-nearest-even
    unsigned u = __float_as_uint(f);
    return (bf16_t)((u + 0x7FFFu + ((u >> 16) & 1u)) >> 16);
}

// --- Strip sort: LDS counting-sort of 4096 directed edges by bucket --------
// binned word = (local_dst[8b]<<18)|src. pos[k*(NB+1)+b] = run start of
// bucket b in strip k; pos[k*(NB+1)+NB] = edge count of strip k.
__global__ void __launch_bounds__(256)
lgcn_bin(const int* __restrict__ row, const int* __restrict__ col,
         int* __restrict__ pos, int* __restrict__ binned, int EH) {
    __shared__ int cnt[NBP];
    __shared__ int sA[256], sB[256];
    __shared__ int base[NB + 2];
    __shared__ int stage[STRIP];
    int tid = threadIdx.x;
    int k = blockIdx.x;
    cnt[tid] = 0; cnt[tid + 256] = 0; cnt[tid + 512] = 0;
    __syncthreads();
    int e0 = k * PAIRS_PER_BLK;
    int e1 = min(EH, e0 + PAIRS_PER_BLK);
    int n = e1 - e0;                           // pairs (multiple of 4)
    int nq = n >> 2;
    const int4* r4 = (const int4*)(row + e0);
    const int4* c4 = (const int4*)(col + e0);
    for (int q = tid; q < nq; q += 256) {
        int4 r = r4[q]; int4 c = c4[q];
        atomicAdd(&cnt[r.x >> BSHIFT], 1); atomicAdd(&cnt[c.x >> BSHIFT], 1);
        atomicAdd(&cnt[r.y >> BSHIFT], 1); atomicAdd(&cnt[c.y >> BSHIFT], 1);
        atomicAdd(&cnt[r.z >> BSHIFT], 1); atomicAdd(&cnt[c.z >> BSHIFT], 1);
        atomicAdd(&cnt[r.w >> BSHIFT], 1); atomicAdd(&cnt[c.w >> BSHIFT], 1);
    }
    __syncthreads();
    // Exclusive scan over NBP buckets, 3 per thread.
    int c0 = cnt[3 * tid], c1 = cnt[3 * tid + 1], c2 = cnt[3 * tid + 2];
    int s = c0 + c1 + c2;
    sA[tid] = s;
    __syncthreads();
    int* c_ = sA; int* n_ = sB;
    for (int off = 1; off < 256; off <<= 1) {
        n_[tid] = (tid >= off) ? c_[tid] + c_[tid - off] : c_[tid];
        __syncthreads();
        int* t = c_; c_ = n_; n_ = t;
    }
    int excl = c_[tid] - s;
    if (3 * tid     <= NB) base[3 * tid]     = excl;
    if (3 * tid + 1 <= NB) base[3 * tid + 1] = excl + c0;
    if (3 * tid + 2 <= NB) base[3 * tid + 2] = excl + c0 + c1;
    __syncthreads();
    // pos table (coalesced) + LDS cursors (reuse cnt).
    for (int i = tid; i <= NB; i += 256) {
        pos[k * (NB + 1) + i] = base[i];
        cnt[i] = base[i];
    }
    __syncthreads();
    // LDS scatter (re-read pairs; L2-hot).
    for (int q = tid; q < nq; q += 256) {
        int4 r = r4[q]; int4 c = c4[q];
        int rr[4] = { r.x, r.y, r.z, r.w };
        int cc[4] = { c.x, c.y, c.z, c.w };
#pragma unroll
        for (int j = 0; j < 4; ++j) {
            int p1 = atomicAdd(&cnt[cc[j] >> BSHIFT], 1);
            stage[p1] = ((cc[j] & (BUCKET - 1)) << 18) | rr[j];
            int p2 = atomicAdd(&cnt[rr[j] >> BSHIFT], 1);
            stage[p2] = ((rr[j] & (BUCKET - 1)) << 18) | cc[j];
        }
    }
    __syncthreads();
    // Coalesced strip write-out.
    int m4 = (2 * n) >> 2;
    int4* dst = (int4*)(binned + k * STRIP);
    const int4* st4 = (const int4*)stage;
    for (int j = tid; j < m4; j += 256) dst[j] = st4[j];
}

// --- Per-bucket padded CSR + fused g0 init ---------------------------------
// Node segments padded to multiple of 4; pad slots = N_NODES (zero row).
// nodeinfo = {start, deg, bits(1/sqrt(da)), bits(sqrt(da))}.
// Scatter goes DIRECTLY to the block's private bucket region in 'packed'.
// Also writes g0 = norm*x (bf16) for this bucket's nodes + zero rows (blk 0).
__global__ void __launch_bounds__(256)
lgcn_build_csr(const int* __restrict__ pos, const int* __restrict__ binned,
               int4* __restrict__ nodeinfo, int* __restrict__ packed,
               const float* __restrict__ ue, const float* __restrict__ ie,
               bf16_t* __restrict__ g0, bf16_t* __restrict__ g1, int nblk) {
    __shared__ int stage[CAP];     // gathered edges of this bucket (32 KB)
    __shared__ int sA[256], sB[256];
    __shared__ int hist[256], cur[256];
    int b = blockIdx.x;
    int tid = threadIdx.x;
    int gb = b << CAPSHIFT;        // this block's private packed region
    // Runs for strips tid and tid+256.
    int a0 = 0, l0 = 0, a1 = 0, l1 = 0;
    if (tid < nblk) {
        const int* pk = pos + tid * (NB + 1) + b;
        a0 = pk[0]; l0 = pk[1] - a0;
    }
    if (tid + 256 < nblk) {
        const int* pk = pos + (tid + 256) * (NB + 1) + b;
        a1 = pk[0]; l1 = pk[1] - a1;
    }
    int u = l0 + l1;
    sA[tid] = u;
    __syncthreads();
    int* c_ = sA; int* n_ = sB;
    for (int off = 1; off < 256; off <<= 1) {
        n_[tid] = (tid >= off) ? c_[tid] + c_[tid - off] : c_[tid];
        __syncthreads();
        int* t = c_; c_ = n_; n_ = t;
    }
    int myBase = c_[tid] - u;
    int Eb = c_[255];
    __syncthreads();
    // Gather runs into stage (short scattered reads, x4 unrolled for MLP).
    {
        const int* s0 = binned + tid * STRIP + a0;
        int i = 0;
        for (; i + 4 <= l0; i += 4) {
            int w0 = s0[i], w1 = s0[i + 1], w2 = s0[i + 2], w3 = s0[i + 3];
            stage[myBase + i] = w0;     stage[myBase + i + 1] = w1;
            stage[myBase + i + 2] = w2; stage[myBase + i + 3] = w3;
        }
        for (; i < l0; ++i) stage[myBase + i] = s0[i];
        const int* s1 = binned + (tid + 256) * STRIP + a1;
        int bb = myBase + l0;
        i = 0;
        for (; i + 4 <= l1; i += 4) {
            int w0 = s1[i], w1 = s1[i + 1], w2 = s1[i + 2], w3 = s1[i + 3];
            stage[bb + i] = w0;     stage[bb + i + 1] = w1;
            stage[bb + i + 2] = w2; stage[bb + i + 3] = w3;
        }
        for (; i < l1; ++i) stage[bb + i] = s1[i];
    }
    hist[tid] = 0;
    __syncthreads();
    for (int j = tid; j < Eb; j += 256)
        atomicAdd(&hist[stage[j] >> 18], 1);
    __syncthreads();
    int deg = hist[tid];
    int degp = (deg + 3) & ~3;               // padded segment length
    sA[tid] = degp;
    __syncthreads();
    int* c2 = sA; int* n2 = sB;
    for (int off = 1; off < 256; off <<= 1) {
        n2[tid] = (tid >= off) ? c2[tid] + c2[tid - off] : c2[tid];
        __syncthreads();
        int* t = c2; c2 = n2; n2 = t;
    }
    int startLoc = c2[tid] - degp;           // local, int4-aligned
    cur[tid] = startLoc;
    int node = (b << BSHIFT) + tid;
    float da = (deg == 0) ? 1.0f : (float)deg;
    float sq = sqrtf(da);
    float nm = 1.0f / sq;
    if (node < N_NODES) {
        int4 ni;
        ni.x = gb + startLoc;
        ni.y = deg;
        ni.z = __float_as_int(nm);
        ni.w = __float_as_int(sq);
        nodeinfo[node] = ni;
    }
    __syncthreads();                          // all hist reads done
    hist[tid] = __float_as_int(nm);           // reuse hist as norm table
    // Pad slots -> zero row (block-owned region; disjoint from scatter).
    for (int kk = deg; kk < degp; ++kk)
        packed[gb + startLoc + kk] = N_NODES;
    // Direct global scatter into the block's private bucket region.
    for (int j = tid; j < Eb; j += 256) {
        int w = stage[j];
        int p = atomicAdd(&cur[w >> 18], 1);  // LDS atomic
        packed[gb + p] = w & 0x3FFFF;
    }
    // --- Fused g0 init for this bucket's nodes (flat chunk range is
    // contiguous: t = b*4096 + i, i in [0, nloc*16)). -----------------------
    int firstNode = b << BSHIFT;
    int nloc = min(BUCKET, N_NODES - firstNode);
    const int nU16 = N_USERS * (DIM / 4);
    int t0 = firstNode * (DIM / 4);
    for (int i = tid; i < nloc * (DIM / 4); i += 256) {
        int t = t0 + i;
        float4 x = (t < nU16) ? ((const float4*)ue)[t]
                              : ((const float4*)ie)[t - nU16];
        float nrm = __int_as_float(hist[i >> 4]);
        ushort4 o;
        o.x = f2bf(x.x * nrm); o.y = f2bf(x.y * nrm);
        o.z = f2bf(x.z * nrm); o.w = f2bf(x.w * nrm);
        ((ushort4*)g0)[t] = o;
    }
    if (b == 0 && tid < 32) {                 // zero rows in both buffers
        const int nT = N_NODES * (DIM / 4);
        if (tid < 16) ((ushort4*)g0)[nT + tid] = make_ushort4(0, 0, 0, 0);
        else          ((ushort4*)g1)[nT + tid - 16] = make_ushort4(0, 0, 0, 0);
    }
}

// --- Propagation (lane = dim) ----------------------------------------------

// Sum rows of g for edges [su, su+dp): wave-uniform su/dp (SGPR), scalar
// edge-quad loads, saddr row reads with loop-invariant lane offset.
static __device__ __forceinline__ float
gather_lane(const bf16_t* __restrict__ g, const int* __restrict__ packed,
            int su, int dp, int lane) {
    float acc = 0.f;
    const int4* p4 = (const int4*)(packed + su);
    int k = 0;
    for (; k + 8 <= dp; k += 8) {            // 8 independent row loads
        int4 ea = p4[k >> 2];
        int4 eb = p4[(k >> 2) + 1];
        const bf16_t* r0 = g + ((unsigned)ea.x << 6);
        const bf16_t* r1 = g + ((unsigned)ea.y << 6);
        const bf16_t* r2 = g + ((unsigned)ea.z << 6);
        const bf16_t* r3 = g + ((unsigned)ea.w << 6);
        const bf16_t* r4 = g + ((unsigned)eb.x << 6);
        const bf16_t* r5 = g + ((unsigned)eb.y << 6);
        const bf16_t* r6 = g + ((unsigned)eb.z << 6);
        const bf16_t* r7 = g + ((unsigned)eb.w << 6);
        float v0 = bf2f(r0[lane]); float v1 = bf2f(r1[lane]);
        float v2 = bf2f(r2[lane]); float v3 = bf2f(r3[lane]);
        float v4 = bf2f(r4[lane]); float v5 = bf2f(r5[lane]);
        float v6 = bf2f(r6[lane]); float v7 = bf2f(r7[lane]);
        acc += ((v0 + v1) + (v2 + v3)) + ((v4 + v5) + (v6 + v7));
    }
    if (k < dp) {                            // tail quad (dp % 8 == 4)
        int4 ea = p4[k >> 2];
        const bf16_t* r0 = g + ((unsigned)ea.x << 6);
        const bf16_t* r1 = g + ((unsigned)ea.y << 6);
        const bf16_t* r2 = g + ((unsigned)ea.z << 6);
        const bf16_t* r3 = g + ((unsigned)ea.w << 6);
        float v0 = bf2f(r0[lane]); float v1 = bf2f(r1[lane]);
        float v2 = bf2f(r2[lane]); float v3 = bf2f(r3[lane]);
        acc += (v0 + v1) + (v2 + v3);
    }
    return acc;
}

// Ranged pull: gn[n] = bf16( norm[n]^2 * sum_{s in N(n)} g[s] ) for
// n in [lo, hi). One node per wave, lane = dim. Bipartite phases: item-dst
// nodes gather only user rows; user-dst nodes gather only item rows —
// ranged dispatches shrink the live source set per pass (L2 residence).
__global__ void __launch_bounds__(256)
lgcn_pull(const bf16_t* __restrict__ g, const int4* __restrict__ nodeinfo,
          const int* __restrict__ packed, bf16_t* __restrict__ gn,
          int lo, int hi) {
    int n = lo + blockIdx.x * 4 + (threadIdx.x >> 6);
    if (n >= hi) return;
    n = __builtin_amdgcn_readfirstlane(n);
    int lane = threadIdx.x & 63;
    int4 ni = nodeinfo[n];
    int su = __builtin_amdgcn_readfirstlane(ni.x);
    int du = __builtin_amdgcn_readfirstlane(ni.y);
    int dp = (du + 3) & ~3;
    float acc = gather_lane(g, packed, su, dp, lane);
    float nm = __int_as_float(ni.z);
    gn[((unsigned)n << 6) + lane] = f2bf(acc * nm * nm);
}

// Fused layer-3 + epilogue, batch nodes only (lane = dim):
// out[slot] = 0.25*( x[n] + rn*g1[n] + rn*g2[n] + nm*sum_{s in N(n)} g2[s] ).
__global__ void __launch_bounds__(256)
lgcn_final(const float* __restrict__ ue, const float* __restrict__ ie,
           const bf16_t* __restrict__ g1, const bf16_t* __restrict__ g2,
           const int4* __restrict__ nodeinfo, const int* __restrict__ packed,
           const int* __restrict__ uid, const int* __restrict__ iid,
           float* __restrict__ out) {
    int slot = blockIdx.x * 4 + (threadIdx.x >> 6);
    if (slot >= 2 * BATCH) return;
    slot = __builtin_amdgcn_readfirstlane(slot);
    int lane = threadIdx.x & 63;
    int isItem = slot >= BATCH;
    int b = isItem ? (slot - BATCH) : slot;
    int node = isItem ? (N_USERS + iid[b]) : uid[b];
    node = __builtin_amdgcn_readfirstlane(node);
    int4 ni = nodeinfo[node];
    int su = __builtin_amdgcn_readfirstlane(ni.x);
    int du = __builtin_amdgcn_readfirstlane(ni.y);
    int dp = (du + 3) & ~3;
    float acc = gather_lane(g2, packed, su, dp, lane);
    const float* xb = isItem ? (ie + ((unsigned)(node - N_USERS) << 6))
                             : (ue + ((unsigned)node << 6));
    float x = xb[lane];
    float a1 = bf2f(g1[((unsigned)node << 6) + lane]);
    float a2 = bf2f(g2[((unsigned)node << 6) + lane]);
    float rn = __int_as_float(ni.w);
    float nm = __int_as_float(ni.z);
    out[((unsigned)slot << 6) + lane] = 0.25f * (x + rn * (a1 + a2) + nm * acc);
}

// --- Launch ----------------------------------------------------------------

extern "C" void kernel_launch(void* const* d_in, const int* in_sizes, int n_in,
                              void* d_out, int out_size, void* d_ws, size_t ws_size,
                              hipStream_t stream) {
    const float* ue  = (const float*)d_in[0];
    const float* ie  = (const float*)d_in[1];
    const int*   ei  = (const int*)d_in[3];
    const int*   uid = (const int*)d_in[4];
    const int*   iid = (const int*)d_in[5];
    float* out = (float*)d_out;

    const int E  = in_sizes[2];     // 2,000,000 directed edges
    const int EH = E / 2;           // 1,000,000 undirected pairs
    const int* row = ei;            // first-half src = user ids
    const int* col = ei + E;        // first-half dst = item node ids

    const int nblk = (EH + PAIRS_PER_BLK - 1) / PAIRS_PER_BLK;   // 489

    // Workspace carve-up (256-B aligned), ~58 MB total.
    char* p = (char*)d_ws;
    size_t off = 0;
    auto carve = [&](size_t bytes) -> char* {
        char* r = p + off;
        off += (bytes + 255) & ~(size_t)255;
        return r;
    };
    const size_t nodeBf16 = (size_t)(N_NODES + 1) * DIM * sizeof(bf16_t); // +zero row
    bf16_t* gA       = (bf16_t*)carve(nodeBf16);
    bf16_t* gB       = (bf16_t*)carve(nodeBf16);
    int4*   nodeinfo = (int4*)carve((size_t)N_NODES * sizeof(int4));       // 2.4 MB
    int*    pos      = (int*)carve((size_t)nblk * (NB + 1) * sizeof(int)); // 1.15 MB
    int*    binned   = (int*)carve((size_t)nblk * STRIP * sizeof(int));    // 8 MB
    int*    packed   = (int*)carve((size_t)NB * CAP * sizeof(int));        // 19.2 MB
    (void)ws_size;

    const int itemGrid = ((N_NODES - N_USERS) + 3) / 4;   // 12500
    const int userGrid = (N_USERS + 3) / 4;               // 25000

    // 1) Strip sort.
    lgcn_bin<<<nblk, 256, 0, stream>>>(row, col, pos, binned, EH);
    // 2) Per-bucket CSR (direct scatter) + fused g0 init + zero rows.
    lgcn_build_csr<<<NB, 256, 0, stream>>>(pos, binned, nodeinfo, packed,
                                           ue, ie, gA, gB, nblk);
    // 3) Layer 1: item-dst phase (gathers user rows, 12.8 MB live set),
    //    then user-dst phase (gathers item rows, 6.4 MB live set).
    lgcn_pull<<<itemGrid, 256, 0, stream>>>(gA, nodeinfo, packed, gB,
                                            N_USERS, N_NODES);
    lgcn_pull<<<userGrid, 256, 0, stream>>>(gA, nodeinfo, packed, gB,
                                            0, N_USERS);
    // 4) Layer 2, same split.
    lgcn_pull<<<itemGrid, 256, 0, stream>>>(gB, nodeinfo, packed, gA,
                                            N_USERS, N_NODES);
    lgcn_pull<<<userGrid, 256, 0, stream>>>(gB, nodeinfo, packed, gA,
                                            0, N_USERS);
    // 5) Fused batch-only layer 3 + epilogue.
    lgcn_final<<<(2 * BATCH + 3) / 4, 256, 0, stream>>>(
        ue, ie, gB, gA, nodeinfo, packed, uid, iid, out);
}

// Round 11
// 223.735 us; speedup vs baseline: 2.7865x; 1.0375x over previous
//
#include <hip/hip_runtime.h>

// LightGCN encoder on MI355X — round 18.
// Round 17 post-mortem: bipartite pull split hurt (-7 us, extra dispatch
// overhead, no fetch win) -> reverted. Counters surfaced build_csr as the
// top dispatch (44 us, VALU 6.7%, Occ 14%): latency-bound on phase A's
// per-thread SEQUENTIAL dependent scattered run-copy (~14 x 500cy chains).
// Fix: FLATTENED GATHER — scan run lengths -> runStart/runAddr in LDS; all
// threads grid-stride j in [0,Eb): 9-step LDS binary search (broadcast-
// friendly) -> stage[j] = binned[runAddr[s] + j - runStart[s]]. Every load
// independent (full MLP), consecutive j coalesce within ~7-word runs.
// LDS overlay (runStart/runAddr alias hist/cur across a barrier): 38 KB,
// 4 blocks/CU unchanged.
// bin / pull / final byte-identical to round 15 (single pull per layer).
#define N_USERS 100000
#define N_NODES 150000
#define DIM 64
#define BATCH 4096
#define BSHIFT 8
#define BUCKET 256
#define NB 586                 // ceil(150000 / 256) buckets
#define NBP 768                // padded bucket count for the 3-per-thread scan
#define PAIRS_PER_BLK 2048     // undirected pairs per binning block
#define STRIP 4096             // directed edges (words) per strip
#define CAPSHIFT 13
#define CAP (1 << CAPSHIFT)    // packed slots per bucket (max ~5.4K used)

typedef unsigned short bf16_t;

static __device__ __forceinline__ float bf2f(bf16_t h) {
    return __uint_as_float(((unsigned)h) << 16);
}
static __device__ __forceinline__ bf16_t f2bf(float f) {  // round-nearest-even
    unsigned u = __float_as_uint(f);
    return (bf16_t)((u + 0x7FFFu + ((u >> 16) & 1u)) >> 16);
}

// --- Strip sort: LDS counting-sort of 4096 directed edges by bucket --------
// binned word = (local_dst[8b]<<18)|src. pos[k*(NB+1)+b] = run start of
// bucket b in strip k; pos[k*(NB+1)+NB] = edge count of strip k.
__global__ void __launch_bounds__(256)
lgcn_bin(const int* __restrict__ row, const int* __restrict__ col,
         int* __restrict__ pos, int* __restrict__ binned, int EH) {
    __shared__ int cnt[NBP];
    __shared__ int sA[256], sB[256];
    __shared__ int base[NB + 2];
    __shared__ int stage[STRIP];
    int tid = threadIdx.x;
    int k = blockIdx.x;
    cnt[tid] = 0; cnt[tid + 256] = 0; cnt[tid + 512] = 0;
    __syncthreads();
    int e0 = k * PAIRS_PER_BLK;
    int e1 = min(EH, e0 + PAIRS_PER_BLK);
    int n = e1 - e0;                           // pairs (multiple of 4)
    int nq = n >> 2;
    const int4* r4 = (const int4*)(row + e0);
    const int4* c4 = (const int4*)(col + e0);
    for (int q = tid; q < nq; q += 256) {
        int4 r = r4[q]; int4 c = c4[q];
        atomicAdd(&cnt[r.x >> BSHIFT], 1); atomicAdd(&cnt[c.x >> BSHIFT], 1);
        atomicAdd(&cnt[r.y >> BSHIFT], 1); atomicAdd(&cnt[c.y >> BSHIFT], 1);
        atomicAdd(&cnt[r.z >> BSHIFT], 1); atomicAdd(&cnt[c.z >> BSHIFT], 1);
        atomicAdd(&cnt[r.w >> BSHIFT], 1); atomicAdd(&cnt[c.w >> BSHIFT], 1);
    }
    __syncthreads();
    // Exclusive scan over NBP buckets, 3 per thread.
    int c0 = cnt[3 * tid], c1 = cnt[3 * tid + 1], c2 = cnt[3 * tid + 2];
    int s = c0 + c1 + c2;
    sA[tid] = s;
    __syncthreads();
    int* c_ = sA; int* n_ = sB;
    for (int off = 1; off < 256; off <<= 1) {
        n_[tid] = (tid >= off) ? c_[tid] + c_[tid - off] : c_[tid];
        __syncthreads();
        int* t = c_; c_ = n_; n_ = t;
    }
    int excl = c_[tid] - s;
    if (3 * tid     <= NB) base[3 * tid]     = excl;
    if (3 * tid + 1 <= NB) base[3 * tid + 1] = excl + c0;
    if (3 * tid + 2 <= NB) base[3 * tid + 2] = excl + c0 + c1;
    __syncthreads();
    // pos table (coalesced) + LDS cursors (reuse cnt).
    for (int i = tid; i <= NB; i += 256) {
        pos[k * (NB + 1) + i] = base[i];
        cnt[i] = base[i];
    }
    __syncthreads();
    // LDS scatter (re-read pairs; L2-hot).
    for (int q = tid; q < nq; q += 256) {
        int4 r = r4[q]; int4 c = c4[q];
        int rr[4] = { r.x, r.y, r.z, r.w };
        int cc[4] = { c.x, c.y, c.z, c.w };
#pragma unroll
        for (int j = 0; j < 4; ++j) {
            int p1 = atomicAdd(&cnt[cc[j] >> BSHIFT], 1);
            stage[p1] = ((cc[j] & (BUCKET - 1)) << 18) | rr[j];
            int p2 = atomicAdd(&cnt[rr[j] >> BSHIFT], 1);
            stage[p2] = ((rr[j] & (BUCKET - 1)) << 18) | cc[j];
        }
    }
    __syncthreads();
    // Coalesced strip write-out.
    int m4 = (2 * n) >> 2;
    int4* dst = (int4*)(binned + k * STRIP);
    const int4* st4 = (const int4*)stage;
    for (int j = tid; j < m4; j += 256) dst[j] = st4[j];
}

// --- Per-bucket padded CSR + fused g0 init ---------------------------------
// Phase A: flattened gather (runStart/runAddr + binary search, independent
// coalesced-ish loads). Phase B: hist/scan/scatter + g0 init, as r15.
// Node segments padded to multiple of 4; pad slots = N_NODES (zero row).
// nodeinfo = {start, deg, bits(1/sqrt(da)), bits(sqrt(da))}.
__global__ void __launch_bounds__(256)
lgcn_build_csr(const int* __restrict__ pos, const int* __restrict__ binned,
               int4* __restrict__ nodeinfo, int* __restrict__ packed,
               const float* __restrict__ ue, const float* __restrict__ ie,
               bf16_t* __restrict__ g0, bf16_t* __restrict__ g1, int nblk) {
    __shared__ int stage[CAP];     // gathered edges of this bucket (32 KB)
    __shared__ int ovl[1025];      // phase A: runStart[513] + runAddr[512]
                                   // phase B: hist[256] + cur[256]
    __shared__ int sA[256], sB[256];
    int b = blockIdx.x;
    int tid = threadIdx.x;
    int gb = b << CAPSHIFT;        // this block's private packed region
    int* runStart = ovl;
    int* runAddr  = ovl + 513;
    // Runs for strips 2*tid and 2*tid+1 (adjacent -> contiguous flat order).
    int s0 = 2 * tid, s1 = 2 * tid + 1;
    int a0 = 0, l0 = 0, a1 = 0, l1 = 0;
    if (s0 < nblk) {
        const int* pk = pos + s0 * (NB + 1) + b;
        a0 = pk[0]; l0 = pk[1] - a0;
    }
    if (s1 < nblk) {
        const int* pk = pos + s1 * (NB + 1) + b;
        a1 = pk[0]; l1 = pk[1] - a1;
    }
    runAddr[s0] = s0 * STRIP + a0;
    runAddr[s1] = s1 * STRIP + a1;
    int u = l0 + l1;
    sA[tid] = u;
    __syncthreads();
    int* c_ = sA; int* n_ = sB;
    for (int off = 1; off < 256; off <<= 1) {
        n_[tid] = (tid >= off) ? c_[tid] + c_[tid - off] : c_[tid];
        __syncthreads();
        int* t = c_; c_ = n_; n_ = t;
    }
    int base2 = c_[tid] - u;
    runStart[s0] = base2;
    runStart[s1] = base2 + l0;
    int Eb = c_[255];
    if (tid == 0) runStart[512] = Eb;
    __syncthreads();
    // Flattened gather: independent loads, consecutive j coalesce in runs.
    for (int j = tid; j < Eb; j += 256) {
        int lo = 0;                           // largest s: runStart[s] <= j
#pragma unroll
        for (int step = 256; step > 0; step >>= 1) {
            int mid = lo + step;
            if (mid <= 511 && runStart[mid] <= j) lo = mid;
        }
        stage[j] = binned[runAddr[lo] + (j - runStart[lo])];
    }
    __syncthreads();                          // runStart/runAddr dead
    int* hist = ovl;                          // overlay phase B
    int* cur  = ovl + 256;
    hist[tid] = 0;
    __syncthreads();
    for (int j = tid; j < Eb; j += 256)
        atomicAdd(&hist[stage[j] >> 18], 1);
    __syncthreads();
    int deg = hist[tid];
    int degp = (deg + 3) & ~3;               // padded segment length
    sA[tid] = degp;
    __syncthreads();
    int* c2 = sA; int* n2 = sB;
    for (int off = 1; off < 256; off <<= 1) {
        n2[tid] = (tid >= off) ? c2[tid] + c2[tid - off] : c2[tid];
        __syncthreads();
        int* t = c2; c2 = n2; n2 = t;
    }
    int startLoc = c2[tid] - degp;           // local, int4-aligned
    cur[tid] = startLoc;
    int node = (b << BSHIFT) + tid;
    float da = (deg == 0) ? 1.0f : (float)deg;
    float sq = sqrtf(da);
    float nm = 1.0f / sq;
    if (node < N_NODES) {
        int4 ni;
        ni.x = gb + startLoc;
        ni.y = deg;
        ni.z = __float_as_int(nm);
        ni.w = __float_as_int(sq);
        nodeinfo[node] = ni;
    }
    __syncthreads();                          // all hist reads done
    hist[tid] = __float_as_int(nm);           // reuse hist as norm table
    // Pad slots -> zero row (block-owned region; disjoint from scatter).
    for (int kk = deg; kk < degp; ++kk)
        packed[gb + startLoc + kk] = N_NODES;
    // Direct global scatter into the block's private bucket region.
    for (int j = tid; j < Eb; j += 256) {
        int w = stage[j];
        int p = atomicAdd(&cur[w >> 18], 1);  // LDS atomic
        packed[gb + p] = w & 0x3FFFF;
    }
    // --- Fused g0 init for this bucket's nodes (flat chunk range is
    // contiguous: t = b*4096 + i, i in [0, nloc*16)). -----------------------
    int firstNode = b << BSHIFT;
    int nloc = min(BUCKET, N_NODES - firstNode);
    const int nU16 = N_USERS * (DIM / 4);
    int t0 = firstNode * (DIM / 4);
    for (int i = tid; i < nloc * (DIM / 4); i += 256) {
        int t = t0 + i;
        float4 x = (t < nU16) ? ((const float4*)ue)[t]
                              : ((const float4*)ie)[t - nU16];
        float nrm = __int_as_float(hist[i >> 4]);
        ushort4 o;
        o.x = f2bf(x.x * nrm); o.y = f2bf(x.y * nrm);
        o.z = f2bf(x.z * nrm); o.w = f2bf(x.w * nrm);
        ((ushort4*)g0)[t] = o;
    }
    if (b == 0 && tid < 32) {                 // zero rows in both buffers
        const int nT = N_NODES * (DIM / 4);
        if (tid < 16) ((ushort4*)g0)[nT + tid] = make_ushort4(0, 0, 0, 0);
        else          ((ushort4*)g1)[nT + tid - 16] = make_ushort4(0, 0, 0, 0);
    }
}

// --- Propagation (lane = dim) ----------------------------------------------

// Sum rows of g for edges [su, su+dp): wave-uniform su/dp (SGPR), scalar
// edge-quad loads, saddr row reads with loop-invariant lane offset.
static __device__ __forceinline__ float
gather_lane(const bf16_t* __restrict__ g, const int* __restrict__ packed,
            int su, int dp, int lane) {
    float acc = 0.f;
    const int4* p4 = (const int4*)(packed + su);
    int k = 0;
    for (; k + 8 <= dp; k += 8) {            // 8 independent row loads
        int4 ea = p4[k >> 2];
        int4 eb = p4[(k >> 2) + 1];
        const bf16_t* r0 = g + ((unsigned)ea.x << 6);
        const bf16_t* r1 = g + ((unsigned)ea.y << 6);
        const bf16_t* r2 = g + ((unsigned)ea.z << 6);
        const bf16_t* r3 = g + ((unsigned)ea.w << 6);
        const bf16_t* r4 = g + ((unsigned)eb.x << 6);
        const bf16_t* r5 = g + ((unsigned)eb.y << 6);
        const bf16_t* r6 = g + ((unsigned)eb.z << 6);
        const bf16_t* r7 = g + ((unsigned)eb.w << 6);
        float v0 = bf2f(r0[lane]); float v1 = bf2f(r1[lane]);
        float v2 = bf2f(r2[lane]); float v3 = bf2f(r3[lane]);
        float v4 = bf2f(r4[lane]); float v5 = bf2f(r5[lane]);
        float v6 = bf2f(r6[lane]); float v7 = bf2f(r7[lane]);
        acc += ((v0 + v1) + (v2 + v3)) + ((v4 + v5) + (v6 + v7));
    }
    if (k < dp) {                            // tail quad (dp % 8 == 4)
        int4 ea = p4[k >> 2];
        const bf16_t* r0 = g + ((unsigned)ea.x << 6);
        const bf16_t* r1 = g + ((unsigned)ea.y << 6);
        const bf16_t* r2 = g + ((unsigned)ea.z << 6);
        const bf16_t* r3 = g + ((unsigned)ea.w << 6);
        float v0 = bf2f(r0[lane]); float v1 = bf2f(r1[lane]);
        float v2 = bf2f(r2[lane]); float v3 = bf2f(r3[lane]);
        acc += (v0 + v1) + (v2 + v3);
    }
    return acc;
}

// Full pull: gn[n] = bf16( norm[n]^2 * sum_{s in N(n)} g[s] ). One node/wave.
__global__ void __launch_bounds__(256)
lgcn_pull(const bf16_t* __restrict__ g, const int4* __restrict__ nodeinfo,
          const int* __restrict__ packed, bf16_t* __restrict__ gn) {
    int n = blockIdx.x * 4 + (threadIdx.x >> 6);
    if (n >= N_NODES) return;
    n = __builtin_amdgcn_readfirstlane(n);
    int lane = threadIdx.x & 63;
    int4 ni = nodeinfo[n];
    int su = __builtin_amdgcn_readfirstlane(ni.x);
    int du = __builtin_amdgcn_readfirstlane(ni.y);
    int dp = (du + 3) & ~3;
    float acc = gather_lane(g, packed, su, dp, lane);
    float nm = __int_as_float(ni.z);
    gn[((unsigned)n << 6) + lane] = f2bf(acc * nm * nm);
}

// Fused layer-3 + epilogue, batch nodes only (lane = dim):
// out[slot] = 0.25*( x[n] + rn*g1[n] + rn*g2[n] + nm*sum_{s in N(n)} g2[s] ).
__global__ void __launch_bounds__(256)
lgcn_final(const float* __restrict__ ue, const float* __restrict__ ie,
           const bf16_t* __restrict__ g1, const bf16_t* __restrict__ g2,
           const int4* __restrict__ nodeinfo, const int* __restrict__ packed,
           const int* __restrict__ uid, const int* __restrict__ iid,
           float* __restrict__ out) {
    int slot = blockIdx.x * 4 + (threadIdx.x >> 6);
    if (slot >= 2 * BATCH) return;
    slot = __builtin_amdgcn_readfirstlane(slot);
    int lane = threadIdx.x & 63;
    int isItem = slot >= BATCH;
    int b = isItem ? (slot - BATCH) : slot;
    int node = isItem ? (N_USERS + iid[b]) : uid[b];
    node = __builtin_amdgcn_readfirstlane(node);
    int4 ni = nodeinfo[node];
    int su = __builtin_amdgcn_readfirstlane(ni.x);
    int du = __builtin_amdgcn_readfirstlane(ni.y);
    int dp = (du + 3) & ~3;
    float acc = gather_lane(g2, packed, su, dp, lane);
    const float* xb = isItem ? (ie + ((unsigned)(node - N_USERS) << 6))
                             : (ue + ((unsigned)node << 6));
    float x = xb[lane];
    float a1 = bf2f(g1[((unsigned)node << 6) + lane]);
    float a2 = bf2f(g2[((unsigned)node << 6) + lane]);
    float rn = __int_as_float(ni.w);
    float nm = __int_as_float(ni.z);
    out[((unsigned)slot << 6) + lane] = 0.25f * (x + rn * (a1 + a2) + nm * acc);
}

// --- Launch ----------------------------------------------------------------

extern "C" void kernel_launch(void* const* d_in, const int* in_sizes, int n_in,
                              void* d_out, int out_size, void* d_ws, size_t ws_size,
                              hipStream_t stream) {
    const float* ue  = (const float*)d_in[0];
    const float* ie  = (const float*)d_in[1];
    const int*   ei  = (const int*)d_in[3];
    const int*   uid = (const int*)d_in[4];
    const int*   iid = (const int*)d_in[5];
    float* out = (float*)d_out;

    const int E  = in_sizes[2];     // 2,000,000 directed edges
    const int EH = E / 2;           // 1,000,000 undirected pairs
    const int* row = ei;            // first-half src = user ids
    const int* col = ei + E;        // first-half dst = item node ids

    const int nblk = (EH + PAIRS_PER_BLK - 1) / PAIRS_PER_BLK;   // 489

    // Workspace carve-up (256-B aligned), ~58 MB total.
    char* p = (char*)d_ws;
    size_t off = 0;
    auto carve = [&](size_t bytes) -> char* {
        char* r = p + off;
        off += (bytes + 255) & ~(size_t)255;
        return r;
    };
    const size_t nodeBf16 = (size_t)(N_NODES + 1) * DIM * sizeof(bf16_t); // +zero row
    bf16_t* gA       = (bf16_t*)carve(nodeBf16);
    bf16_t* gB       = (bf16_t*)carve(nodeBf16);
    int4*   nodeinfo = (int4*)carve((size_t)N_NODES * sizeof(int4));       // 2.4 MB
    int*    pos      = (int*)carve((size_t)nblk * (NB + 1) * sizeof(int)); // 1.15 MB
    int*    binned   = (int*)carve((size_t)nblk * STRIP * sizeof(int));    // 8 MB
    int*    packed   = (int*)carve((size_t)NB * CAP * sizeof(int));        // 19.2 MB
    (void)ws_size;

    // 1) Strip sort.
    lgcn_bin<<<nblk, 256, 0, stream>>>(row, col, pos, binned, EH);
    // 2) Per-bucket CSR (flattened gather, direct scatter) + fused g0 init.
    lgcn_build_csr<<<NB, 256, 0, stream>>>(pos, binned, nodeinfo, packed,
                                           ue, ie, gA, gB, nblk);
    // 3) Two full pulls (1 node/wave, lane=dim), then batch-only epilogue.
    const int pullGrid = (N_NODES + 3) / 4;        // 37500
    lgcn_pull<<<pullGrid, 256, 0, stream>>>(gA, nodeinfo, packed, gB);  // g1 = gB
    lgcn_pull<<<pullGrid, 256, 0, stream>>>(gB, nodeinfo, packed, gA);  // g2 = gA
    lgcn_final<<<(2 * BATCH + 3) / 4, 256, 0, stream>>>(
        ue, ie, gB, gA, nodeinfo, packed, uid, iid, out);
}

// Round 12
// 223.547 us; speedup vs baseline: 2.7888x; 1.0008x over previous
//
#include <hip/hip_runtime.h>

// LightGCN encoder on MI355X — round 19.
// Round 18 post-mortem: flatten bought ~2 us; plateau ~223. r17's csr
// counters re-read: Occ 14% at 36KB LDS is a GRID problem — 586 blocks =
// 2.3/CU on a latency-chain kernel. bin likewise (489 = 1.9/CU).
// Round 19: halve the tile grain to double preprocessing parallelism.
//   BUCKET 256->128 (NB 1172, CAP 4096): csr 1172 blocks, ~26 KB LDS,
//     fully resident, per-block phases halve.
//   PAIRS_PER_BLK 2048->1024 (977 strips, STRIP 2048): bin 977 blocks.
//   Scans: bin 5 buckets/thread, csr 4 strips/thread (1024-entry run table,
//   10-step search). pull / final byte-identical (absolute starts).
#define N_USERS 100000
#define N_NODES 150000
#define DIM 64
#define BATCH 4096
#define BSHIFT 7
#define BUCKET 128
#define NB 1172                // ceil(150000 / 128) buckets
#define NBP 1280               // padded bucket count for the 5-per-thread scan
#define PAIRS_PER_BLK 1024     // undirected pairs per binning block
#define STRIP 2048             // directed edges (words) per strip
#define CAPSHIFT 12
#define CAP (1 << CAPSHIFT)    // packed slots per bucket (max ~3.1K used)

typedef unsigned short bf16_t;

static __device__ __forceinline__ float bf2f(bf16_t h) {
    return __uint_as_float(((unsigned)h) << 16);
}
static __device__ __forceinline__ bf16_t f2bf(float f) {  // round-nearest-even
    unsigned u = __float_as_uint(f);
    return (bf16_t)((u + 0x7FFFu + ((u >> 16) & 1u)) >> 16);
}

// --- Strip sort: LDS counting-sort of 2048 directed edges by bucket --------
// binned word = (local_dst[7b]<<18)|src. pos[k*(NB+1)+b] = run start of
// bucket b in strip k; pos[k*(NB+1)+NB] = edge count of strip k.
__global__ void __launch_bounds__(256)
lgcn_bin(const int* __restrict__ row, const int* __restrict__ col,
         int* __restrict__ pos, int* __restrict__ binned, int EH) {
    __shared__ int cnt[NBP];
    __shared__ int sA[256], sB[256];
    __shared__ int base[NB + 2];
    __shared__ int stage[STRIP];
    int tid = threadIdx.x;
    int k = blockIdx.x;
    cnt[tid] = 0; cnt[tid + 256] = 0; cnt[tid + 512] = 0;
    cnt[tid + 768] = 0; cnt[tid + 1024] = 0;
    __syncthreads();
    int e0 = k * PAIRS_PER_BLK;
    int e1 = min(EH, e0 + PAIRS_PER_BLK);
    int n = e1 - e0;                           // pairs (multiple of 4)
    int nq = n >> 2;
    const int4* r4 = (const int4*)(row + e0);
    const int4* c4 = (const int4*)(col + e0);
    for (int q = tid; q < nq; q += 256) {
        int4 r = r4[q]; int4 c = c4[q];
        atomicAdd(&cnt[r.x >> BSHIFT], 1); atomicAdd(&cnt[c.x >> BSHIFT], 1);
        atomicAdd(&cnt[r.y >> BSHIFT], 1); atomicAdd(&cnt[c.y >> BSHIFT], 1);
        atomicAdd(&cnt[r.z >> BSHIFT], 1); atomicAdd(&cnt[c.z >> BSHIFT], 1);
        atomicAdd(&cnt[r.w >> BSHIFT], 1); atomicAdd(&cnt[c.w >> BSHIFT], 1);
    }
    __syncthreads();
    // Exclusive scan over NBP buckets, 5 per thread.
    int b5 = 5 * tid;
    int c0 = cnt[b5], c1 = cnt[b5 + 1], c2 = cnt[b5 + 2];
    int c3 = cnt[b5 + 3], c4v = cnt[b5 + 4];
    int s = c0 + c1 + c2 + c3 + c4v;
    sA[tid] = s;
    __syncthreads();
    int* c_ = sA; int* n_ = sB;
    for (int off = 1; off < 256; off <<= 1) {
        n_[tid] = (tid >= off) ? c_[tid] + c_[tid - off] : c_[tid];
        __syncthreads();
        int* t = c_; c_ = n_; n_ = t;
    }
    int excl = c_[tid] - s;
    if (b5     <= NB) base[b5]     = excl;
    if (b5 + 1 <= NB) base[b5 + 1] = excl + c0;
    if (b5 + 2 <= NB) base[b5 + 2] = excl + c0 + c1;
    if (b5 + 3 <= NB) base[b5 + 3] = excl + c0 + c1 + c2;
    if (b5 + 4 <= NB) base[b5 + 4] = excl + c0 + c1 + c2 + c3;
    __syncthreads();
    // pos table (coalesced) + LDS cursors (reuse cnt).
    for (int i = tid; i <= NB; i += 256) {
        pos[k * (NB + 1) + i] = base[i];
        cnt[i] = base[i];
    }
    __syncthreads();
    // LDS scatter (re-read pairs; L2-hot).
    for (int q = tid; q < nq; q += 256) {
        int4 r = r4[q]; int4 c = c4[q];
        int rr[4] = { r.x, r.y, r.z, r.w };
        int cc[4] = { c.x, c.y, c.z, c.w };
#pragma unroll
        for (int j = 0; j < 4; ++j) {
            int p1 = atomicAdd(&cnt[cc[j] >> BSHIFT], 1);
            stage[p1] = ((cc[j] & (BUCKET - 1)) << 18) | rr[j];
            int p2 = atomicAdd(&cnt[rr[j] >> BSHIFT], 1);
            stage[p2] = ((rr[j] & (BUCKET - 1)) << 18) | cc[j];
        }
    }
    __syncthreads();
    // Coalesced strip write-out.
    int m4 = (2 * n) >> 2;
    int4* dst = (int4*)(binned + k * STRIP);
    const int4* st4 = (const int4*)stage;
    for (int j = tid; j < m4; j += 256) dst[j] = st4[j];
}

// --- Per-bucket padded CSR + fused g0 init ---------------------------------
// Phase A: flattened gather (runStart/runAddr + 10-step binary search,
// independent loads). Phase B: hist/scan/scatter + g0 init.
// Node segments padded to multiple of 4; pad slots = N_NODES (zero row).
// nodeinfo = {start, deg, bits(1/sqrt(da)), bits(sqrt(da))}.
__global__ void __launch_bounds__(256)
lgcn_build_csr(const int* __restrict__ pos, const int* __restrict__ binned,
               int4* __restrict__ nodeinfo, int* __restrict__ packed,
               const float* __restrict__ ue, const float* __restrict__ ie,
               bf16_t* __restrict__ g0, bf16_t* __restrict__ g1, int nblk) {
    __shared__ int stage[CAP];     // gathered edges of this bucket (16 KB)
    __shared__ int ovl[2048];      // phase A: runStart[1024] + runAddr[1024]
                                   // phase B: hist[256] + cur[256]
    __shared__ int sA[256], sB[256];
    int b = blockIdx.x;
    int tid = threadIdx.x;
    int gb = b << CAPSHIFT;        // this block's private packed region
    int* runStart = ovl;
    int* runAddr  = ovl + 1024;
    // Runs for strips 4*tid .. 4*tid+3 (adjacent -> contiguous flat order).
    int ll[4];
    int u = 0;
#pragma unroll
    for (int q = 0; q < 4; ++q) {
        int sidx = 4 * tid + q;
        int av = 0, lv = 0;
        if (sidx < nblk) {
            const int* pk = pos + sidx * (NB + 1) + b;
            av = pk[0]; lv = pk[1] - av;
        }
        runAddr[sidx] = sidx * STRIP + av;
        ll[q] = lv;
        u += lv;
    }
    sA[tid] = u;
    __syncthreads();
    int* c_ = sA; int* n_ = sB;
    for (int off = 1; off < 256; off <<= 1) {
        n_[tid] = (tid >= off) ? c_[tid] + c_[tid - off] : c_[tid];
        __syncthreads();
        int* t = c_; c_ = n_; n_ = t;
    }
    int run0 = c_[tid] - u;
    int Eb = c_[255];
#pragma unroll
    for (int q = 0; q < 4; ++q) {
        runStart[4 * tid + q] = run0;
        run0 += ll[q];
    }
    __syncthreads();
    // Flattened gather: independent loads; beyond-nblk entries hold Eb
    // (monotone) so the search never selects them.
    for (int j = tid; j < Eb; j += 256) {
        int lo = 0;                           // largest s: runStart[s] <= j
#pragma unroll
        for (int step = 512; step > 0; step >>= 1) {
            int mid = lo + step;
            if (mid <= 1023 && runStart[mid] <= j) lo = mid;
        }
        stage[j] = binned[runAddr[lo] + (j - runStart[lo])];
    }
    __syncthreads();                          // runStart/runAddr dead
    int* hist = ovl;                          // overlay phase B
    int* cur  = ovl + 256;
    hist[tid] = 0;
    __syncthreads();
    for (int j = tid; j < Eb; j += 256)
        atomicAdd(&hist[stage[j] >> 18], 1);
    __syncthreads();
    int deg = hist[tid];                      // 0 for tid >= BUCKET
    int degp = (deg + 3) & ~3;               // padded segment length
    sA[tid] = degp;
    __syncthreads();
    int* c2 = sA; int* n2 = sB;
    for (int off = 1; off < 256; off <<= 1) {
        n2[tid] = (tid >= off) ? c2[tid] + c2[tid - off] : c2[tid];
        __syncthreads();
        int* t = c2; c2 = n2; n2 = t;
    }
    int startLoc = c2[tid] - degp;           // local, int4-aligned
    cur[tid] = startLoc;
    int node = (b << BSHIFT) + tid;
    float da = (deg == 0) ? 1.0f : (float)deg;
    float sq = sqrtf(da);
    float nm = 1.0f / sq;
    if (tid < BUCKET && node < N_NODES) {
        int4 ni;
        ni.x = gb + startLoc;
        ni.y = deg;
        ni.z = __float_as_int(nm);
        ni.w = __float_as_int(sq);
        nodeinfo[node] = ni;
    }
    __syncthreads();                          // all hist reads done
    hist[tid] = __float_as_int(nm);           // reuse hist as norm table
    // Pad slots -> zero row (block-owned region; disjoint from scatter).
    for (int kk = deg; kk < degp; ++kk)
        packed[gb + startLoc + kk] = N_NODES;
    // Direct global scatter into the block's private bucket region.
    for (int j = tid; j < Eb; j += 256) {
        int w = stage[j];
        int p = atomicAdd(&cur[w >> 18], 1);  // LDS atomic
        packed[gb + p] = w & 0x3FFFF;
    }
    // --- Fused g0 init for this bucket's nodes (flat chunk range is
    // contiguous: t = b*2048 + i, i in [0, nloc*16)). -----------------------
    int firstNode = b << BSHIFT;
    int nloc = min(BUCKET, N_NODES - firstNode);
    const int nU16 = N_USERS * (DIM / 4);
    int t0 = firstNode * (DIM / 4);
    for (int i = tid; i < nloc * (DIM / 4); i += 256) {
        int t = t0 + i;
        float4 x = (t < nU16) ? ((const float4*)ue)[t]
                              : ((const float4*)ie)[t - nU16];
        float nrm = __int_as_float(hist[i >> 4]);
        ushort4 o;
        o.x = f2bf(x.x * nrm); o.y = f2bf(x.y * nrm);
        o.z = f2bf(x.z * nrm); o.w = f2bf(x.w * nrm);
        ((ushort4*)g0)[t] = o;
    }
    if (b == 0 && tid < 32) {                 // zero rows in both buffers
        const int nT = N_NODES * (DIM / 4);
        if (tid < 16) ((ushort4*)g0)[nT + tid] = make_ushort4(0, 0, 0, 0);
        else          ((ushort4*)g1)[nT + tid - 16] = make_ushort4(0, 0, 0, 0);
    }
}

// --- Propagation (lane = dim) ----------------------------------------------

// Sum rows of g for edges [su, su+dp): wave-uniform su/dp (SGPR), scalar
// edge-quad loads, saddr row reads with loop-invariant lane offset.
static __device__ __forceinline__ float
gather_lane(const bf16_t* __restrict__ g, const int* __restrict__ packed,
            int su, int dp, int lane) {
    float acc = 0.f;
    const int4* p4 = (const int4*)(packed + su);
    int k = 0;
    for (; k + 8 <= dp; k += 8) {            // 8 independent row loads
        int4 ea = p4[k >> 2];
        int4 eb = p4[(k >> 2) + 1];
        const bf16_t* r0 = g + ((unsigned)ea.x << 6);
        const bf16_t* r1 = g + ((unsigned)ea.y << 6);
        const bf16_t* r2 = g + ((unsigned)ea.z << 6);
        const bf16_t* r3 = g + ((unsigned)ea.w << 6);
        const bf16_t* r4 = g + ((unsigned)eb.x << 6);
        const bf16_t* r5 = g + ((unsigned)eb.y << 6);
        const bf16_t* r6 = g + ((unsigned)eb.z << 6);
        const bf16_t* r7 = g + ((unsigned)eb.w << 6);
        float v0 = bf2f(r0[lane]); float v1 = bf2f(r1[lane]);
        float v2 = bf2f(r2[lane]); float v3 = bf2f(r3[lane]);
        float v4 = bf2f(r4[lane]); float v5 = bf2f(r5[lane]);
        float v6 = bf2f(r6[lane]); float v7 = bf2f(r7[lane]);
        acc += ((v0 + v1) + (v2 + v3)) + ((v4 + v5) + (v6 + v7));
    }
    if (k < dp) {                            // tail quad (dp % 8 == 4)
        int4 ea = p4[k >> 2];
        const bf16_t* r0 = g + ((unsigned)ea.x << 6);
        const bf16_t* r1 = g + ((unsigned)ea.y << 6);
        const bf16_t* r2 = g + ((unsigned)ea.z << 6);
        const bf16_t* r3 = g + ((unsigned)ea.w << 6);
        float v0 = bf2f(r0[lane]); float v1 = bf2f(r1[lane]);
        float v2 = bf2f(r2[lane]); float v3 = bf2f(r3[lane]);
        acc += (v0 + v1) + (v2 + v3);
    }
    return acc;
}

// Full pull: gn[n] = bf16( norm[n]^2 * sum_{s in N(n)} g[s] ). One node/wave.
__global__ void __launch_bounds__(256)
lgcn_pull(const bf16_t* __restrict__ g, const int4* __restrict__ nodeinfo,
          const int* __restrict__ packed, bf16_t* __restrict__ gn) {
    int n = blockIdx.x * 4 + (threadIdx.x >> 6);
    if (n >= N_NODES) return;
    n = __builtin_amdgcn_readfirstlane(n);
    int lane = threadIdx.x & 63;
    int4 ni = nodeinfo[n];
    int su = __builtin_amdgcn_readfirstlane(ni.x);
    int du = __builtin_amdgcn_readfirstlane(ni.y);
    int dp = (du + 3) & ~3;
    float acc = gather_lane(g, packed, su, dp, lane);
    float nm = __int_as_float(ni.z);
    gn[((unsigned)n << 6) + lane] = f2bf(acc * nm * nm);
}

// Fused layer-3 + epilogue, batch nodes only (lane = dim):
// out[slot] = 0.25*( x[n] + rn*g1[n] + rn*g2[n] + nm*sum_{s in N(n)} g2[s] ).
__global__ void __launch_bounds__(256)
lgcn_final(const float* __restrict__ ue, const float* __restrict__ ie,
           const bf16_t* __restrict__ g1, const bf16_t* __restrict__ g2,
           const int4* __restrict__ nodeinfo, const int* __restrict__ packed,
           const int* __restrict__ uid, const int* __restrict__ iid,
           float* __restrict__ out) {
    int slot = blockIdx.x * 4 + (threadIdx.x >> 6);
    if (slot >= 2 * BATCH) return;
    slot = __builtin_amdgcn_readfirstlane(slot);
    int lane = threadIdx.x & 63;
    int isItem = slot >= BATCH;
    int b = isItem ? (slot - BATCH) : slot;
    int node = isItem ? (N_USERS + iid[b]) : uid[b];
    node = __builtin_amdgcn_readfirstlane(node);
    int4 ni = nodeinfo[node];
    int su = __builtin_amdgcn_readfirstlane(ni.x);
    int du = __builtin_amdgcn_readfirstlane(ni.y);
    int dp = (du + 3) & ~3;
    float acc = gather_lane(g2, packed, su, dp, lane);
    const float* xb = isItem ? (ie + ((unsigned)(node - N_USERS) << 6))
                             : (ue + ((unsigned)node << 6));
    float x = xb[lane];
    float a1 = bf2f(g1[((unsigned)node << 6) + lane]);
    float a2 = bf2f(g2[((unsigned)node << 6) + lane]);
    float rn = __int_as_float(ni.w);
    float nm = __int_as_float(ni.z);
    out[((unsigned)slot << 6) + lane] = 0.25f * (x + rn * (a1 + a2) + nm * acc);
}

// --- Launch ----------------------------------------------------------------

extern "C" void kernel_launch(void* const* d_in, const int* in_sizes, int n_in,
                              void* d_out, int out_size, void* d_ws, size_t ws_size,
                              hipStream_t stream) {
    const float* ue  = (const float*)d_in[0];
    const float* ie  = (const float*)d_in[1];
    const int*   ei  = (const int*)d_in[3];
    const int*   uid = (const int*)d_in[4];
    const int*   iid = (const int*)d_in[5];
    float* out = (float*)d_out;

    const int E  = in_sizes[2];     // 2,000,000 directed edges
    const int EH = E / 2;           // 1,000,000 undirected pairs
    const int* row = ei;            // first-half src = user ids
    const int* col = ei + E;        // first-half dst = item node ids

    const int nblk = (EH + PAIRS_PER_BLK - 1) / PAIRS_PER_BLK;   // 977

    // Workspace carve-up (256-B aligned), ~73 MB total.
    char* p = (char*)d_ws;
    size_t off = 0;
    auto carve = [&](size_t bytes) -> char* {
        char* r = p + off;
        off += (bytes + 255) & ~(size_t)255;
        return r;
    };
    const size_t nodeBf16 = (size_t)(N_NODES + 1) * DIM * sizeof(bf16_t); // +zero row
    bf16_t* gA       = (bf16_t*)carve(nodeBf16);
    bf16_t* gB       = (bf16_t*)carve(nodeBf16);
    int4*   nodeinfo = (int4*)carve((size_t)N_NODES * sizeof(int4));       // 2.4 MB
    int*    pos      = (int*)carve((size_t)nblk * (NB + 1) * sizeof(int)); // 4.6 MB
    int*    binned   = (int*)carve((size_t)nblk * STRIP * sizeof(int));    // 8 MB
    int*    packed   = (int*)carve((size_t)NB * CAP * sizeof(int));        // 19.2 MB
    (void)ws_size;

    // 1) Strip sort.
    lgcn_bin<<<nblk, 256, 0, stream>>>(row, col, pos, binned, EH);
    // 2) Per-bucket CSR (flattened gather, direct scatter) + fused g0 init.
    lgcn_build_csr<<<NB, 256, 0, stream>>>(pos, binned, nodeinfo, packed,
                                           ue, ie, gA, gB, nblk);
    // 3) Two full pulls (1 node/wave, lane=dim), then batch-only epilogue.
    const int pullGrid = (N_NODES + 3) / 4;        // 37500
    lgcn_pull<<<pullGrid, 256, 0, stream>>>(gA, nodeinfo, packed, gB);  // g1 = gB
    lgcn_pull<<<pullGrid, 256, 0, stream>>>(gB, nodeinfo, packed, gA);  // g2 = gA
    lgcn_final<<<(2 * BATCH + 3) / 4, 256, 0, stream>>>(
        ue, ie, gB, gA, nodeinfo, packed, uid, iid, out);
}